// Round 2
// 116.455 us; speedup vs baseline: 1.0470x; 1.0470x over previous
//
#include <hip/hip_runtime.h>

#define IN_DIM 128
#define CAP 128           // adjacency bucket capacity (deg~Poisson(16); P(>=128)~1e-120)
#define LDT 136           // padded per-wave Ts row stride (ushorts)
#define SCAT_BLOCKS 384   // grid-stride scatter blocks

typedef short v8s __attribute__((ext_vector_type(8)));   // 8 bf16 (4 VGPRs)
typedef float v4f __attribute__((ext_vector_type(4)));   // MFMA acc

__device__ inline unsigned short f2bf(float f) {
    unsigned int u = __float_as_uint(f);
    u += 0x7FFFu + ((u >> 16) & 1u);          // round-to-nearest-even
    return (unsigned short)(u >> 16);
}
__device__ inline float bf2f(unsigned short h) {
    return __uint_as_float((unsigned int)h << 16);
}
// tanh(x) = 1 - 2/(e^{2x}+1); v_exp_f32 + v_rcp_f32, ~1ulp each -> err ~1e-6,
// invisible under bf16 rounding. Saturates to +/-1 cleanly (inf -> rcp=0).
__device__ inline float fast_tanh(float x) {
    float e = __builtin_amdgcn_exp2f(x * 2.885390081777927f);   // e^{2x}
    return 1.0f - 2.0f * __builtin_amdgcn_rcpf(e + 1.0f);
}

// ---------------------------------------------------------------------------
// R17 (resubmit after infra flake): barrier-free mlp_fill. Ts was already
// wave-private; the ONLY reason R12 had barriers was the LDS-shared W tile.
// W is 32KB/phase (L2-hot), so each wave now reads its own B-fragments
// straight from global in a FRAGMENT-ORDERED layout (prep writes Wf so that
// one (kk,ct) fragment is a single fully-coalesced dwordx4 per wave:
// offset ((kk*8+ct)*64+lane)*16B).
// -> zero __syncthreads, LDS 67.6KB -> 34KB, 2 -> 3 blocks/CU, no vmcnt(0)
// drains on the critical path. Plus fast_tanh replaces 64 libm tanhf/thread.
//
// prep (one dispatch, three independent sub-grids):
//   blocks [0,128):        W1/W2 fp32 (k-major) -> bf16 fragment layout Wf:
//                          Wf[(kk*8+ct)*64 + quad*16+l15][j] =
//                          W[(kk*32+quad*8+j)*128 + ct*16+l15]
//   blocks [128,128+nbF):  flag[node_idx[i]] = 1 (poison-tolerant: ==1 test)
//   blocks [128+nbF,+nbC): cursor[v] = 0
// ---------------------------------------------------------------------------
__global__ __launch_bounds__(256) void prep(
    const float* __restrict__ W1, const float* __restrict__ W2,
    unsigned short* __restrict__ Wf1, unsigned short* __restrict__ Wf2,
    const int* __restrict__ node_idx, int* __restrict__ flag, int B,
    int* __restrict__ cursor, int N, int nbF)
{
    int bid = blockIdx.x;
    if (bid < 128) {
        int i = bid * 256 + threadIdx.x;   // 0..32767
        int m = i >> 14, o = i & 16383;
        int j   = o & 7;
        int l15 = (o >> 3) & 15;
        int quad = (o >> 7) & 3;
        int ct  = (o >> 9) & 7;
        int kk  = (o >> 12) & 3;
        int k = kk * 32 + quad * 8 + j;
        int n = ct * 16 + l15;
        float wv = (m ? W2 : W1)[k * 128 + n];
        (m ? Wf2 : Wf1)[o] = f2bf(wv);     // writes coalesced
    } else if (bid < 128 + nbF) {
        int i = (bid - 128) * 256 + threadIdx.x;
        if (i < B) flag[node_idx[i]] = 1;
    } else {
        int i = (bid - 128 - nbF) * 256 + threadIdx.x;
        if (i < N) cursor[i] = 0;
    }
}

// ---------------------------------------------------------------------------
// Fused MLP + grid-stride edge scatter. MLP path is now a pure per-wave
// pipeline: phase1 (X from HBM, W1 frags from L1/L2) -> fast_tanh -> Ts
// (wave-private LDS) -> phase2 (Ts ds_reads, W2 frags) -> Hb store.
// No __syncthreads anywhere. LDS = Ts only (34816B) -> 3 blocks/CU with
// __launch_bounds__(256,3).
//
// Frag maps (m89/m91-verified): A[m=lane&15][k=quad*8+j];
// B[n=lane&15][k=quad*8+j]; C/D col=lane&15, row=quad*4+reg.
//
// Scatter blocks (uniform branch, return immediately — no barriers exist):
// kept edge (src!=dst or mask[ind]!=0) with flag[src]==1:
// col[src*CAP + cursor[src]++] = dst. deg==row_sum exactly.
// ---------------------------------------------------------------------------
__global__ __launch_bounds__(256, 3) void mlp_fill(
    const float* __restrict__ X,
    const unsigned short* __restrict__ Wf1, const unsigned short* __restrict__ Wf2,
    const float* __restrict__ b1, const float* __restrict__ b2,
    unsigned short* __restrict__ Hb, int nrows,
    const int* __restrict__ edges, const int* __restrict__ flag,
    const int* __restrict__ indp, int* __restrict__ cursor,
    unsigned short* __restrict__ col, int E, int mlpBlocks)
{
    const int bid = blockIdx.x;

    if (bid >= mlpBlocks) {
        // ---- grid-stride edge scatter (no LDS touch, no barriers) ----
        const int keepSelf = (*indp < 2) ? 1 : 0;
        const int stride = SCAT_BLOCKS * 256;
        for (int e = (bid - mlpBlocks) * 256 + threadIdx.x; e < E; e += stride) {
            int2 ed = ((const int2*)edges)[e];
            if ((ed.x != ed.y || keepSelf) && flag[ed.x] == 1) {
                int p = atomicAdd(&cursor[ed.x], 1);   // ~16-way/node, cheap
                if (p < CAP)
                    col[(size_t)ed.x * CAP + p] = (unsigned short)ed.y;
            }
        }
        return;
    }

    // ---- MLP (wave-private, barrier-free) ----
    __shared__ unsigned short Ts[4 * 32 * LDT];         // 34816 B, per-wave
    const int t    = threadIdx.x;
    const int w    = t >> 6;
    const int lane = t & 63;
    const int l15  = lane & 15;
    const int quad = lane >> 4;
    const int R0   = bid * 128;
    const int wrow = w * 32;
    unsigned short* Tw = &Ts[w * 32 * LDT];

    // wave's two A-row base pointers (clamped once)
    int gr0 = R0 + wrow + l15;        gr0 = gr0 < nrows ? gr0 : nrows - 1;
    int gr1 = R0 + wrow + 16 + l15;   gr1 = gr1 < nrows ? gr1 : nrows - 1;
    const float* xrow[2] = { &X[(size_t)gr0 * 128 + quad * 8],
                             &X[(size_t)gr1 * 128 + quad * 8] };

    // per-lane fragment pointers: fragment (kk,ct) = one coalesced dwordx4/wave
    const v8s* Wp1 = (const v8s*)Wf1 + lane;
    const v8s* Wp2 = (const v8s*)Wf2 + lane;

    v4f acc[2][8];
#pragma unroll
    for (int rt = 0; rt < 2; ++rt)
#pragma unroll
        for (int ct = 0; ct < 8; ++ct)
            acc[rt][ct] = (v4f){0.f, 0.f, 0.f, 0.f};

    // ---- phase 1: T = tanh(X @ W1 + b1) ----
#pragma unroll
    for (int kk = 0; kk < 4; ++kk) {
        v8s Ar[2];
#pragma unroll
        for (int rt = 0; rt < 2; ++rt) {
            const float* xp = xrow[rt] + kk * 32;
            float4 x0 = *(const float4*)xp;
            float4 x1 = *(const float4*)(xp + 4);
            v8s av;
            av[0] = (short)f2bf(x0.x); av[1] = (short)f2bf(x0.y);
            av[2] = (short)f2bf(x0.z); av[3] = (short)f2bf(x0.w);
            av[4] = (short)f2bf(x1.x); av[5] = (short)f2bf(x1.y);
            av[6] = (short)f2bf(x1.z); av[7] = (short)f2bf(x1.w);
            Ar[rt] = av;
        }
#pragma unroll
        for (int ct = 0; ct < 8; ++ct) {
            v8s Bfc = Wp1[(kk * 8 + ct) * 64];
            acc[0][ct] = __builtin_amdgcn_mfma_f32_16x16x32_bf16(
                Ar[0], Bfc, acc[0][ct], 0, 0, 0);
            acc[1][ct] = __builtin_amdgcn_mfma_f32_16x16x32_bf16(
                Ar[1], Bfc, acc[1][ct], 0, 0, 0);
        }
    }
    // epilogue 1: fast tanh -> per-wave LDS Ts (bf16, C-layout scatter)
#pragma unroll
    for (int ct = 0; ct < 8; ++ct) {
        float bias = b1[ct * 16 + l15];
#pragma unroll
        for (int rt = 0; rt < 2; ++rt) {
#pragma unroll
            for (int r = 0; r < 4; ++r)
                Tw[(rt * 16 + quad * 4 + r) * LDT + ct * 16 + l15] =
                    f2bf(fast_tanh(acc[rt][ct][r] + bias));
            acc[rt][ct] = (v4f){0.f, 0.f, 0.f, 0.f};
        }
    }

    // no barrier: Ts is wave-private; in-wave DS ordering + compiler lgkmcnt
    // cover the RAW into phase 2.

    // ---- phase 2: H = T @ W2 + b2 ----
#pragma unroll
    for (int kk = 0; kk < 4; ++kk) {
        v8s Ar[2];
#pragma unroll
        for (int rt = 0; rt < 2; ++rt)
            Ar[rt] = *(const v8s*)
                &Tw[(rt * 16 + l15) * LDT + kk * 32 + quad * 8];
#pragma unroll
        for (int ct = 0; ct < 8; ++ct) {
            v8s Bfc = Wp2[(kk * 8 + ct) * 64];
            acc[0][ct] = __builtin_amdgcn_mfma_f32_16x16x32_bf16(
                Ar[0], Bfc, acc[0][ct], 0, 0, 0);
            acc[1][ct] = __builtin_amdgcn_mfma_f32_16x16x32_bf16(
                Ar[1], Bfc, acc[1][ct], 0, 0, 0);
        }
    }
    asm volatile("s_waitcnt lgkmcnt(0)" ::: "memory");  // phase-2 Ts reads done
    // epilogue 2: acc -> per-wave LDS (bf16) -> coalesced dwordx4 H stores
#pragma unroll
    for (int ct = 0; ct < 8; ++ct) {
        float bias = b2[ct * 16 + l15];
#pragma unroll
        for (int rt = 0; rt < 2; ++rt)
#pragma unroll
            for (int r = 0; r < 4; ++r)
                Tw[(rt * 16 + quad * 4 + r) * LDT + ct * 16 + l15] =
                    f2bf(acc[rt][ct][r] + bias);
    }
    asm volatile("s_waitcnt lgkmcnt(0)" ::: "memory");
#pragma unroll
    for (int i = 0; i < 8; ++i) {
        int lr = i * 4 + quad;             // 0..31
        int c  = l15;                      // 16 chunks x 8 ushorts = 128
        uint4 v = *(const uint4*)&Tw[lr * LDT + c * 8];
        int grow = R0 + wrow + lr;
        if (grow < nrows)
            *(uint4*)&Hb[(size_t)grow * 128 + c * 8] = v;
    }
}

// ---------------------------------------------------------------------------
// Fused aggregate+gather: one wave per OUTPUT row b. v=node_idx[b];
// out[b] = (sum_i Hb[col[v*CAP+i]]) / max(deg,1), deg = cursor[v].
// Bucket indices fetched ONCE coalesced (cp[lane]) then __shfl-broadcast.
// Hb bf16: 4B/lane -> 256B coalesced row gather, no atomics.
// ---------------------------------------------------------------------------
__global__ __launch_bounds__(256) void aggregate_out(
    const int* __restrict__ node_idx, const int* __restrict__ cursor,
    const unsigned short* __restrict__ col, const unsigned short* __restrict__ Hb,
    float* __restrict__ out, int B)
{
    int b = (int)((blockIdx.x * blockDim.x + threadIdx.x) >> 6);
    if (b >= B) return;
    int lane = threadIdx.x & 63;
    int v = node_idx[b];
    int deg = cursor[v];
    deg = deg < CAP ? deg : CAP;
    const unsigned short* cp = &col[(size_t)v * CAP];
    int myc = (lane < deg) ? (int)cp[lane] : 0;   // one coalesced bucket load
    int dmax = deg < 64 ? deg : 64;
    float ax = 0.f, ay = 0.f, bx = 0.f, by = 0.f;
    int i = 0;
    for (; i + 1 < dmax; i += 2) {
        int d0 = __shfl(myc, i, 64);
        int d1 = __shfl(myc, i + 1, 64);
        unsigned int u0 = *(const unsigned int*)&Hb[(size_t)d0 * 128 + lane * 2];
        unsigned int u1 = *(const unsigned int*)&Hb[(size_t)d1 * 128 + lane * 2];
        ax += bf2f((unsigned short)(u0 & 0xFFFFu));
        ay += bf2f((unsigned short)(u0 >> 16));
        bx += bf2f((unsigned short)(u1 & 0xFFFFu));
        by += bf2f((unsigned short)(u1 >> 16));
    }
    if (i < dmax) {
        int d0 = __shfl(myc, i, 64);
        unsigned int u0 = *(const unsigned int*)&Hb[(size_t)d0 * 128 + lane * 2];
        ax += bf2f((unsigned short)(u0 & 0xFFFFu));
        ay += bf2f((unsigned short)(u0 >> 16));
    }
    for (int j = 64; j < deg; ++j) {              // P~0 tail (deg>64)
        int d0 = cp[j];
        unsigned int u0 = *(const unsigned int*)&Hb[(size_t)d0 * 128 + lane * 2];
        ax += bf2f((unsigned short)(u0 & 0xFFFFu));
        ay += bf2f((unsigned short)(u0 >> 16));
    }
    float den = (deg > 0) ? (float)deg : 1.0f;
    *(float2*)&out[(size_t)b * 128 + lane * 2] =
        make_float2((ax + bx) / den, (ay + by) / den);
}

extern "C" void kernel_launch(void* const* d_in, const int* in_sizes, int n_in,
                              void* d_out, int out_size, void* d_ws, size_t ws_size,
                              hipStream_t stream)
{
    const int*   edges    = (const int*)d_in[0];
    const int*   node_idx = (const int*)d_in[1];
    const float* X        = (const float*)d_in[2];
    const float* W1       = (const float*)d_in[3];
    const float* b1       = (const float*)d_in[4];
    const float* W2       = (const float*)d_in[5];
    const float* b2       = (const float*)d_in[6];
    const int*   indp     = (const int*)d_in[7];

    const int E = in_sizes[0] / 2;
    const int B = in_sizes[1];
    const int N = in_sizes[2] / IN_DIM;
    const int mlpBlocks = (N + 127) / 128;   // 391
    const int nbF = (B + 255) / 256;         // 40
    const int nbC = (N + 255) / 256;         // 196

    // workspace layout (NO memset — flag is poison-tolerant (==1 test),
    // cursor zeroed inside prep, everything else fully overwritten):
    // [cursor N i32][flag N i32][Hb N*128 bf16][col N*CAP u16][Wf1][Wf2]
    char* ws = (char*)d_ws;
    size_t off = 0;
    int* cursor = (int*)(ws + off); off += (size_t)N * 4;
    int* flag   = (int*)(ws + off); off += (size_t)N * 4;
    off = (off + 15) & ~(size_t)15;
    unsigned short* Hb  = (unsigned short*)(ws + off); off += (size_t)N * IN_DIM * 2;
    unsigned short* col = (unsigned short*)(ws + off); off += (size_t)N * CAP * 2;
    unsigned short* Wf1 = (unsigned short*)(ws + off); off += 16384 * 2;
    unsigned short* Wf2 = (unsigned short*)(ws + off); off += 16384 * 2;

    hipLaunchKernelGGL(prep, dim3(128 + nbF + nbC), dim3(256), 0, stream,
                       W1, W2, Wf1, Wf2, node_idx, flag, B, cursor, N, nbF);
    hipLaunchKernelGGL(mlp_fill, dim3(mlpBlocks + SCAT_BLOCKS), dim3(256),
                       0, stream, X, Wf1, Wf2, b1, b2, Hb, N,
                       edges, flag, indp, cursor, col, E, mlpBlocks);
    hipLaunchKernelGGL(aggregate_out, dim3((B * 64 + 255) / 256), dim3(256), 0,
                       stream, node_idx, cursor, col, Hb, (float*)d_out, B);
}

// Round 3
// 110.262 us; speedup vs baseline: 1.1058x; 1.0562x over previous
//
#include <hip/hip_runtime.h>

#define IN_DIM 128
#define CAP 128           // adjacency bucket capacity (deg~Poisson(16); P(>=128)~1e-120)
#define LDT 136           // padded per-wave Ts row stride (ushorts)
#define SCAT_BLOCKS 377   // 391 mlp + 377 scat = 768 = 256 CU x 3 blocks (one residency round)

typedef short v8s __attribute__((ext_vector_type(8)));   // 8 bf16 (4 VGPRs)
typedef float v4f __attribute__((ext_vector_type(4)));   // MFMA acc

__device__ inline unsigned short f2bf(float f) {
    unsigned int u = __float_as_uint(f);
    u += 0x7FFFu + ((u >> 16) & 1u);          // round-to-nearest-even
    return (unsigned short)(u >> 16);
}
__device__ inline float bf2f(unsigned short h) {
    return __uint_as_float((unsigned int)h << 16);
}
// tanh(x) = 1 - 2/(e^{2x}+1); v_exp_f32 + v_rcp_f32, ~1ulp each -> err ~1e-6,
// invisible under bf16 rounding. Saturates to +/-1 cleanly (inf -> rcp=0).
__device__ inline float fast_tanh(float x) {
    float e = __builtin_amdgcn_exp2f(x * 2.885390081777927f);   // e^{2x}
    return 1.0f - 2.0f * __builtin_amdgcn_rcpf(e + 1.0f);
}

// ---------------------------------------------------------------------------
// R18: R17 (116.5us, passed) + latency-ILP rewrite of aggregate_out.
//
// prep (one dispatch, three independent sub-grids):
//   blocks [0,128):        W1/W2 fp32 (k-major) -> bf16 fragment layout Wf:
//                          Wf[(kk*8+ct)*64 + quad*16+l15][j] =
//                          W[(kk*32+quad*8+j)*128 + ct*16+l15]
//   blocks [128,128+nbF):  flag[node_idx[i]] = 1 (poison-tolerant: ==1 test)
//   blocks [128+nbF,+nbC): cursor[v] = 0
// ---------------------------------------------------------------------------
__global__ __launch_bounds__(256) void prep(
    const float* __restrict__ W1, const float* __restrict__ W2,
    unsigned short* __restrict__ Wf1, unsigned short* __restrict__ Wf2,
    const int* __restrict__ node_idx, int* __restrict__ flag, int B,
    int* __restrict__ cursor, int N, int nbF)
{
    int bid = blockIdx.x;
    if (bid < 128) {
        int i = bid * 256 + threadIdx.x;   // 0..32767
        int m = i >> 14, o = i & 16383;
        int j   = o & 7;
        int l15 = (o >> 3) & 15;
        int quad = (o >> 7) & 3;
        int ct  = (o >> 9) & 7;
        int kk  = (o >> 12) & 3;
        int k = kk * 32 + quad * 8 + j;
        int n = ct * 16 + l15;
        float wv = (m ? W2 : W1)[k * 128 + n];
        (m ? Wf2 : Wf1)[o] = f2bf(wv);     // writes coalesced
    } else if (bid < 128 + nbF) {
        int i = (bid - 128) * 256 + threadIdx.x;
        if (i < B) flag[node_idx[i]] = 1;
    } else {
        int i = (bid - 128 - nbF) * 256 + threadIdx.x;
        if (i < N) cursor[i] = 0;
    }
}

// ---------------------------------------------------------------------------
// Fused MLP + grid-stride edge scatter (R17 structure, barrier-free).
// MLP: phase1 (X from HBM, W1 frags from L1/L2) -> fast_tanh -> Ts
// (wave-private LDS) -> phase2 (Ts ds_reads, W2 frags) -> Hb store.
// No __syncthreads. LDS = Ts only (34816B) -> 3 blocks/CU.
//
// Frag maps (m89/m91-verified): A[m=lane&15][k=quad*8+j];
// B[n=lane&15][k=quad*8+j]; C/D col=lane&15, row=quad*4+reg.
//
// Scatter blocks (uniform branch, return immediately — no barriers exist):
// kept edge (src!=dst or mask[ind]!=0) with flag[src]==1:
// col[src*CAP + cursor[src]++] = dst. deg==row_sum exactly.
// ---------------------------------------------------------------------------
__global__ __launch_bounds__(256, 3) void mlp_fill(
    const float* __restrict__ X,
    const unsigned short* __restrict__ Wf1, const unsigned short* __restrict__ Wf2,
    const float* __restrict__ b1, const float* __restrict__ b2,
    unsigned short* __restrict__ Hb, int nrows,
    const int* __restrict__ edges, const int* __restrict__ flag,
    const int* __restrict__ indp, int* __restrict__ cursor,
    unsigned short* __restrict__ col, int E, int mlpBlocks)
{
    const int bid = blockIdx.x;

    if (bid >= mlpBlocks) {
        // ---- grid-stride edge scatter (no LDS touch, no barriers) ----
        const int keepSelf = (*indp < 2) ? 1 : 0;
        const int stride = SCAT_BLOCKS * 256;
        for (int e = (bid - mlpBlocks) * 256 + threadIdx.x; e < E; e += stride) {
            int2 ed = ((const int2*)edges)[e];
            if ((ed.x != ed.y || keepSelf) && flag[ed.x] == 1) {
                int p = atomicAdd(&cursor[ed.x], 1);   // ~16-way/node, cheap
                if (p < CAP)
                    col[(size_t)ed.x * CAP + p] = (unsigned short)ed.y;
            }
        }
        return;
    }

    // ---- MLP (wave-private, barrier-free) ----
    __shared__ unsigned short Ts[4 * 32 * LDT];         // 34816 B, per-wave
    const int t    = threadIdx.x;
    const int w    = t >> 6;
    const int lane = t & 63;
    const int l15  = lane & 15;
    const int quad = lane >> 4;
    const int R0   = bid * 128;
    const int wrow = w * 32;
    unsigned short* Tw = &Ts[w * 32 * LDT];

    // wave's two A-row base pointers (clamped once)
    int gr0 = R0 + wrow + l15;        gr0 = gr0 < nrows ? gr0 : nrows - 1;
    int gr1 = R0 + wrow + 16 + l15;   gr1 = gr1 < nrows ? gr1 : nrows - 1;
    const float* xrow[2] = { &X[(size_t)gr0 * 128 + quad * 8],
                             &X[(size_t)gr1 * 128 + quad * 8] };

    // per-lane fragment pointers: fragment (kk,ct) = one coalesced dwordx4/wave
    const v8s* Wp1 = (const v8s*)Wf1 + lane;
    const v8s* Wp2 = (const v8s*)Wf2 + lane;

    v4f acc[2][8];
#pragma unroll
    for (int rt = 0; rt < 2; ++rt)
#pragma unroll
        for (int ct = 0; ct < 8; ++ct)
            acc[rt][ct] = (v4f){0.f, 0.f, 0.f, 0.f};

    // ---- phase 1: T = tanh(X @ W1 + b1) ----
#pragma unroll
    for (int kk = 0; kk < 4; ++kk) {
        v8s Ar[2];
#pragma unroll
        for (int rt = 0; rt < 2; ++rt) {
            const float* xp = xrow[rt] + kk * 32;
            float4 x0 = *(const float4*)xp;
            float4 x1 = *(const float4*)(xp + 4);
            v8s av;
            av[0] = (short)f2bf(x0.x); av[1] = (short)f2bf(x0.y);
            av[2] = (short)f2bf(x0.z); av[3] = (short)f2bf(x0.w);
            av[4] = (short)f2bf(x1.x); av[5] = (short)f2bf(x1.y);
            av[6] = (short)f2bf(x1.z); av[7] = (short)f2bf(x1.w);
            Ar[rt] = av;
        }
#pragma unroll
        for (int ct = 0; ct < 8; ++ct) {
            v8s Bfc = Wp1[(kk * 8 + ct) * 64];
            acc[0][ct] = __builtin_amdgcn_mfma_f32_16x16x32_bf16(
                Ar[0], Bfc, acc[0][ct], 0, 0, 0);
            acc[1][ct] = __builtin_amdgcn_mfma_f32_16x16x32_bf16(
                Ar[1], Bfc, acc[1][ct], 0, 0, 0);
        }
    }
    // epilogue 1: fast tanh -> per-wave LDS Ts (bf16, C-layout scatter)
#pragma unroll
    for (int ct = 0; ct < 8; ++ct) {
        float bias = b1[ct * 16 + l15];
#pragma unroll
        for (int rt = 0; rt < 2; ++rt) {
#pragma unroll
            for (int r = 0; r < 4; ++r)
                Tw[(rt * 16 + quad * 4 + r) * LDT + ct * 16 + l15] =
                    f2bf(fast_tanh(acc[rt][ct][r] + bias));
            acc[rt][ct] = (v4f){0.f, 0.f, 0.f, 0.f};
        }
    }

    // no barrier: Ts is wave-private; in-wave DS ordering + compiler lgkmcnt
    // cover the RAW into phase 2.

    // ---- phase 2: H = T @ W2 + b2 ----
#pragma unroll
    for (int kk = 0; kk < 4; ++kk) {
        v8s Ar[2];
#pragma unroll
        for (int rt = 0; rt < 2; ++rt)
            Ar[rt] = *(const v8s*)
                &Tw[(rt * 16 + l15) * LDT + kk * 32 + quad * 8];
#pragma unroll
        for (int ct = 0; ct < 8; ++ct) {
            v8s Bfc = Wp2[(kk * 8 + ct) * 64];
            acc[0][ct] = __builtin_amdgcn_mfma_f32_16x16x32_bf16(
                Ar[0], Bfc, acc[0][ct], 0, 0, 0);
            acc[1][ct] = __builtin_amdgcn_mfma_f32_16x16x32_bf16(
                Ar[1], Bfc, acc[1][ct], 0, 0, 0);
        }
    }
    asm volatile("s_waitcnt lgkmcnt(0)" ::: "memory");  // phase-2 Ts reads done
    // epilogue 2: acc -> per-wave LDS (bf16) -> coalesced dwordx4 H stores
#pragma unroll
    for (int ct = 0; ct < 8; ++ct) {
        float bias = b2[ct * 16 + l15];
#pragma unroll
        for (int rt = 0; rt < 2; ++rt)
#pragma unroll
            for (int r = 0; r < 4; ++r)
                Tw[(rt * 16 + quad * 4 + r) * LDT + ct * 16 + l15] =
                    f2bf(acc[rt][ct][r] + bias);
    }
    asm volatile("s_waitcnt lgkmcnt(0)" ::: "memory");
#pragma unroll
    for (int i = 0; i < 8; ++i) {
        int lr = i * 4 + quad;             // 0..31
        int c  = l15;                      // 16 chunks x 8 ushorts = 128
        uint4 v = *(const uint4*)&Tw[lr * LDT + c * 8];
        int grow = R0 + wrow + lr;
        if (grow < nrows)
            *(uint4*)&Hb[(size_t)grow * 128 + c * 8] = v;
    }
}

// ---------------------------------------------------------------------------
// R18 aggregate: one wave per OUTPUT row b. v = node_idx[b] is WAVE-UNIFORM
// -> readfirstlane makes cursor/col accesses SCALAR (s_load), no shuffles.
// Gather runs in chunks of 16 fully-independent row loads in flight
// (SGPR-base row addr + lane offset). Masked chunk slots clamp the index to
// deg-1 (re-fetch a cached row, no wasted lines) and zero the VALUE via
// cndmask before accumulating (poison-safe: never multiplies garbage).
// 4-bin accumulators keep the FP add chains short.
// ---------------------------------------------------------------------------
__global__ __launch_bounds__(256) void aggregate_out(
    const int* __restrict__ node_idx, const int* __restrict__ cursor,
    const unsigned short* __restrict__ col, const unsigned short* __restrict__ Hb,
    float* __restrict__ out, int B)
{
    int b = (int)((blockIdx.x * blockDim.x + threadIdx.x) >> 6);
    if (b >= B) return;
    int lane = threadIdx.x & 63;
    int v = __builtin_amdgcn_readfirstlane(node_idx[b]);   // wave-uniform -> SGPR
    int deg = cursor[v];                                   // scalar load
    deg = deg < CAP ? deg : CAP;
    const unsigned short* cp = &col[(size_t)v * CAP];

    float sx[4] = {0.f, 0.f, 0.f, 0.f};
    float sy[4] = {0.f, 0.f, 0.f, 0.f};
    for (int c0 = 0; c0 < deg; c0 += 16) {
        unsigned int u[16];
#pragma unroll
        for (int k = 0; k < 16; ++k) {
            int idx = c0 + k;
            idx = idx < deg ? idx : deg - 1;        // scalar clamp (deg>=1 here)
            int d = (int)cp[idx];                   // scalar (uniform) load
            u[k] = *(const unsigned int*)&Hb[(size_t)d * 128 + lane * 2];
        }
        int dn = deg - c0;                          // valid slots this chunk
#pragma unroll
        for (int k = 0; k < 16; ++k) {
            unsigned int uv = (k < dn) ? u[k] : 0u; // zero VALUE, not weight
            sx[k & 3] += bf2f((unsigned short)(uv & 0xFFFFu));
            sy[k & 3] += bf2f((unsigned short)(uv >> 16));
        }
    }
    float den = (deg > 0) ? (float)deg : 1.0f;
    float ox = ((sx[0] + sx[1]) + (sx[2] + sx[3])) / den;
    float oy = ((sy[0] + sy[1]) + (sy[2] + sy[3])) / den;
    *(float2*)&out[(size_t)b * 128 + lane * 2] = make_float2(ox, oy);
}

extern "C" void kernel_launch(void* const* d_in, const int* in_sizes, int n_in,
                              void* d_out, int out_size, void* d_ws, size_t ws_size,
                              hipStream_t stream)
{
    const int*   edges    = (const int*)d_in[0];
    const int*   node_idx = (const int*)d_in[1];
    const float* X        = (const float*)d_in[2];
    const float* W1       = (const float*)d_in[3];
    const float* b1       = (const float*)d_in[4];
    const float* W2       = (const float*)d_in[5];
    const float* b2       = (const float*)d_in[6];
    const int*   indp     = (const int*)d_in[7];

    const int E = in_sizes[0] / 2;
    const int B = in_sizes[1];
    const int N = in_sizes[2] / IN_DIM;
    const int mlpBlocks = (N + 127) / 128;   // 391
    const int nbF = (B + 255) / 256;         // 40
    const int nbC = (N + 255) / 256;         // 196

    // workspace layout (NO memset — flag is poison-tolerant (==1 test),
    // cursor zeroed inside prep, everything else fully overwritten):
    // [cursor N i32][flag N i32][Hb N*128 bf16][col N*CAP u16][Wf1][Wf2]
    char* ws = (char*)d_ws;
    size_t off = 0;
    int* cursor = (int*)(ws + off); off += (size_t)N * 4;
    int* flag   = (int*)(ws + off); off += (size_t)N * 4;
    off = (off + 15) & ~(size_t)15;
    unsigned short* Hb  = (unsigned short*)(ws + off); off += (size_t)N * IN_DIM * 2;
    unsigned short* col = (unsigned short*)(ws + off); off += (size_t)N * CAP * 2;
    unsigned short* Wf1 = (unsigned short*)(ws + off); off += 16384 * 2;
    unsigned short* Wf2 = (unsigned short*)(ws + off); off += 16384 * 2;

    hipLaunchKernelGGL(prep, dim3(128 + nbF + nbC), dim3(256), 0, stream,
                       W1, W2, Wf1, Wf2, node_idx, flag, B, cursor, N, nbF);
    hipLaunchKernelGGL(mlp_fill, dim3(mlpBlocks + SCAT_BLOCKS), dim3(256),
                       0, stream, X, Wf1, Wf2, b1, b2, Hb, N,
                       edges, flag, indp, cursor, col, E, mlpBlocks);
    hipLaunchKernelGGL(aggregate_out, dim3((B * 64 + 255) / 256), dim3(256), 0,
                       stream, node_idx, cursor, col, Hb, (float*)d_out, B);
}